// Round 2
// baseline (7407.223 us; speedup 1.0000x reference)
//
#include <hip/hip_runtime.h>
#include <cstdint>
#include <cstddef>

#define B_    256
#define W_    41
#define D_    512
#define K_    4096
#define L_    8
#define NROWS (B_ * W_)            // 10496
#define QOUT_ELEMS (NROWS * D_)    // 5373952

#define BM 128
#define BN 128
#define BKD 16
#define NT (D_ / BKD)              // 32 k-tiles

// -------- init: residual = x, rowNorm[n] = (float)sum(x^2), arm keys --------
__global__ __launch_bounds__(256)
void rq_init(const float* __restrict__ x, float* __restrict__ R,
             float* __restrict__ rowNorm, unsigned long long* __restrict__ keys,
             double* __restrict__ lossAcc)
{
    if (blockIdx.x == 0 && threadIdx.x == 0) *lossAcc = 0.0;
    const int wave = threadIdx.x >> 6;
    const int lane = threadIdx.x & 63;
    const int n = blockIdx.x * 4 + wave;
    const float4* xp = (const float4*)(x + (size_t)n * D_);
    float4* rp = (float4*)(R + (size_t)n * D_);
    double asum = 0.0;
#pragma unroll
    for (int u = 0; u < 2; ++u) {
        const int idx = u * 64 + lane;
        float4 v = xp[idx];
        rp[idx] = v;
        asum += (double)v.x * v.x + (double)v.y * v.y
              + (double)v.z * v.z + (double)v.w * v.w;
    }
#pragma unroll
    for (int off = 32; off > 0; off >>= 1)
        asum += __shfl_down(asum, off, 64);
    if (lane == 0) {
        rowNorm[n] = (float)asum;
        keys[n] = 0xFFFFFFFFFFFFFFFFull;
    }
}

// -------- distance GEMM + argmin --------
// M[n][k] = ascending-d fp32 FMA chain (bit-matches BLAS sgemm per element).
// comparator c = fl(rowNorm - 2*M); key = (bits(c)<<32)|k; u64 min ==
// lexicographic (c,k) min == np.argmin first-index tie rule.
// Micro-tile split 4+4 at distance 64 so LDS fragment reads are <=2-way
// (free) instead of 4-way bank-conflicted.
__global__ __launch_bounds__(256)
void rq_dist_argmin(const float* __restrict__ R, const float* __restrict__ E,
                    const float* __restrict__ rowNorm,
                    unsigned long long* __restrict__ keys)
{
    __shared__ float As[2][BKD][BM];
    __shared__ float Bs[2][BKD][BN];

    const int t  = threadIdx.x;
    const int tx = t & 15;
    const int ty = t >> 4;
    const int rowBase = blockIdx.y * BM;   // y = row tile (82)
    const int colBase = blockIdx.x * BN;   // x = col tile (32): same-row tiles adjacent in dispatch order -> L2 reuse of A
    const int lm   = t >> 1;               // 0..127: tile row loaded by this thread
    const int lseg = (t & 1) * 8;          // 0 or 8: d-offset within 16-wide slab

    const float* Aptr = R + (size_t)(rowBase + lm) * D_ + lseg;
    const float* Bptr = E + (size_t)(colBase + lm) * D_ + lseg;

    float acc[8][8];
#pragma unroll
    for (int i = 0; i < 8; ++i)
#pragma unroll
        for (int j = 0; j < 8; ++j) acc[i][j] = 0.0f;

    // preload tile 0
    float4 pa0 = *(const float4*)(Aptr);
    float4 pa1 = *(const float4*)(Aptr + 4);
    float4 pb0 = *(const float4*)(Bptr);
    float4 pb1 = *(const float4*)(Bptr + 4);
    {
        As[0][lseg + 0][lm] = pa0.x; As[0][lseg + 1][lm] = pa0.y;
        As[0][lseg + 2][lm] = pa0.z; As[0][lseg + 3][lm] = pa0.w;
        As[0][lseg + 4][lm] = pa1.x; As[0][lseg + 5][lm] = pa1.y;
        As[0][lseg + 6][lm] = pa1.z; As[0][lseg + 7][lm] = pa1.w;
        Bs[0][lseg + 0][lm] = pb0.x; Bs[0][lseg + 1][lm] = pb0.y;
        Bs[0][lseg + 2][lm] = pb0.z; Bs[0][lseg + 3][lm] = pb0.w;
        Bs[0][lseg + 4][lm] = pb1.x; Bs[0][lseg + 5][lm] = pb1.y;
        Bs[0][lseg + 6][lm] = pb1.z; Bs[0][lseg + 7][lm] = pb1.w;
    }
    __syncthreads();

    int buf = 0;
    for (int tile = 0; tile < NT; ++tile) {
        float4 na0, na1, nb0, nb1;
        const bool more = (tile + 1) < NT;
        if (more) {
            const int dt = (tile + 1) * BKD;
            na0 = *(const float4*)(Aptr + dt);
            na1 = *(const float4*)(Aptr + dt + 4);
            nb0 = *(const float4*)(Bptr + dt);
            nb1 = *(const float4*)(Bptr + dt + 4);
        }
#pragma unroll
        for (int dd = 0; dd < BKD; ++dd) {   // ascending d: exact chain order
            float a[8], b[8];
            *(float4*)&a[0] = *(const float4*)&As[buf][dd][ty * 4];
            *(float4*)&a[4] = *(const float4*)&As[buf][dd][ty * 4 + 64];
            *(float4*)&b[0] = *(const float4*)&Bs[buf][dd][tx * 4];
            *(float4*)&b[4] = *(const float4*)&Bs[buf][dd][tx * 4 + 64];
#pragma unroll
            for (int i = 0; i < 8; ++i)
#pragma unroll
                for (int j = 0; j < 8; ++j)
                    acc[i][j] = fmaf(a[i], b[j], acc[i][j]);
        }
        if (more) {
            const int nb = buf ^ 1;
            As[nb][lseg + 0][lm] = na0.x; As[nb][lseg + 1][lm] = na0.y;
            As[nb][lseg + 2][lm] = na0.z; As[nb][lseg + 3][lm] = na0.w;
            As[nb][lseg + 4][lm] = na1.x; As[nb][lseg + 5][lm] = na1.y;
            As[nb][lseg + 6][lm] = na1.z; As[nb][lseg + 7][lm] = na1.w;
            Bs[nb][lseg + 0][lm] = nb0.x; Bs[nb][lseg + 1][lm] = nb0.y;
            Bs[nb][lseg + 2][lm] = nb0.z; Bs[nb][lseg + 3][lm] = nb0.w;
            Bs[nb][lseg + 4][lm] = nb1.x; Bs[nb][lseg + 5][lm] = nb1.y;
            Bs[nb][lseg + 6][lm] = nb1.z; Bs[nb][lseg + 7][lm] = nb1.w;
        }
        __syncthreads();
        buf ^= 1;
    }

    // epilogue: per-thread keys, shuffle-reduce across tx (lane bits 0..3),
    // then one atomicMin per (row, tx==0) lane.
#pragma unroll
    for (int i = 0; i < 8; ++i) {
        const int rl = ty * 4 + (i & 3) + ((i >= 4) ? 64 : 0);
        const float An = rowNorm[rowBase + rl];
        unsigned long long best = 0xFFFFFFFFFFFFFFFFull;
#pragma unroll
        for (int j = 0; j < 8; ++j) {
            const int col = colBase + tx * 4 + (j & 3) + ((j >= 4) ? 64 : 0);
            const float c = __fsub_rn(An, 2.0f * acc[i][j]);  // c > 0 always
            const unsigned long long key =
                ((unsigned long long)__float_as_uint(c) << 32)
                | (unsigned int)col;
            if (key < best) best = key;
        }
#pragma unroll
        for (int m = 1; m < 16; m <<= 1) {
            const unsigned long long o = __shfl_xor(best, m, 64);
            if (o < best) best = o;
        }
        if (tx == 0)
            atomicMin(&keys[rowBase + rl], best);
    }
}

// -------- per-layer update: STE epilogue, exact fp32 replication --------
__global__ __launch_bounds__(256)
void rq_update(float* __restrict__ R, const float* __restrict__ E,
               unsigned long long* __restrict__ keys,
               float* __restrict__ qout, float* __restrict__ idxOut,
               float* __restrict__ rowNorm, double* __restrict__ lossAcc,
               int layer)
{
    const int wave = threadIdx.x >> 6;
    const int lane = threadIdx.x & 63;
    const int n = blockIdx.x * 4 + wave;
    const unsigned long long key = keys[n];
    const int k = (int)(key & 0xFFFFFFFFull);

    const float4* ep = (const float4*)(E + (size_t)k * D_);
    float4* rp = (float4*)(R + (size_t)n * D_);
    float4* qp = (float4*)(qout + (size_t)n * D_);

    double lsum = 0.0, asum = 0.0;
#pragma unroll
    for (int u = 0; u < 2; ++u) {
        const int idx = u * 64 + lane;
        float4 r4 = rp[idx];
        float4 q4 = ep[idx];
        float4 o4 = (layer == 0) ? make_float4(0.f, 0.f, 0.f, 0.f) : qp[idx];
        float rnew[4], qo[4];
        float rr[4] = {r4.x, r4.y, r4.z, r4.w};
        float qq[4] = {q4.x, q4.y, q4.z, q4.w};
        float oo[4] = {o4.x, o4.y, o4.z, o4.w};
#pragma unroll
        for (int c = 0; c < 4; ++c) {
            const float d1  = __fsub_rn(qq[c], rr[c]);   // quantized - residual
            const float qst = __fadd_rn(rr[c], d1);      // straight-through value
            rnew[c] = __fsub_rn(rr[c], qst);
            qo[c]   = __fadd_rn(oo[c], qst);
            lsum += (double)d1 * (double)d1;
            asum += (double)rnew[c] * (double)rnew[c];
        }
        rp[idx] = make_float4(rnew[0], rnew[1], rnew[2], rnew[3]);
        qp[idx] = make_float4(qo[0], qo[1], qo[2], qo[3]);
    }
#pragma unroll
    for (int off = 32; off > 0; off >>= 1) {
        lsum += __shfl_down(lsum, off, 64);
        asum += __shfl_down(asum, off, 64);
    }
    if (lane == 0) {
        rowNorm[n] = (float)asum;
        keys[n] = 0xFFFFFFFFFFFFFFFFull;   // re-arm for next layer
        atomicAdd(lossAcc, lsum);
        idxOut[(size_t)n * L_ + layer] = (float)k;
    }
}

__global__ void rq_finalize(float* __restrict__ lossOut,
                            const double* __restrict__ lossAcc)
{
    *lossOut = (float)(0.25 * (*lossAcc) / (double)QOUT_ELEMS);
}

extern "C" void kernel_launch(void* const* d_in, const int* in_sizes, int n_in,
                              void* d_out, int out_size, void* d_ws, size_t ws_size,
                              hipStream_t stream)
{
    const float* x  = (const float*)d_in[0];
    const float* cb = (const float*)d_in[1];
    float* out = (float*)d_out;
    char* ws = (char*)d_ws;

    float* R = (float*)ws;                                     // 21,495,808 B
    float* rowNorm = (float*)(ws + 21495808);                  //     41,984 B
    unsigned long long* keys = (unsigned long long*)(ws + 21537792); // 83,968 B
    double* lossAcc = (double*)(ws + 21621760);                //          8 B

    float* idxOut = out + QOUT_ELEMS + 1;

    rq_init<<<NROWS / 4, 256, 0, stream>>>(x, R, rowNorm, keys, lossAcc);

    for (int l = 0; l < L_; ++l) {
        const float* E = cb + (size_t)l * K_ * D_;
        dim3 grid(K_ / BN, NROWS / BM);   // x = col tile, y = row tile
        rq_dist_argmin<<<grid, 256, 0, stream>>>(R, E, rowNorm, keys);
        rq_update<<<NROWS / 4, 256, 0, stream>>>(R, E, keys, out, idxOut,
                                                 rowNorm, lossAcc, l);
    }
    rq_finalize<<<1, 1, 0, stream>>>(out + QOUT_ELEMS, lossAcc);
}

// Round 3
// 5339.154 us; speedup vs baseline: 1.3873x; 1.3873x over previous
//
#include <hip/hip_runtime.h>
#include <cstdint>
#include <cstddef>

#define B_    256
#define W_    41
#define D_    512
#define K_    4096
#define L_    8
#define NROWS (B_ * W_)            // 10496
#define QOUT_ELEMS (NROWS * D_)    // 5373952

#define BM 128
#define BN 128
#define BKD 8

// -------- init: residual = x, rowNorm[n] = (float)sum(x^2), arm keys --------
__global__ __launch_bounds__(256)
void rq_init(const float* __restrict__ x, float* __restrict__ R,
             float* __restrict__ rowNorm, unsigned long long* __restrict__ keys,
             double* __restrict__ lossAcc)
{
    if (blockIdx.x == 0 && threadIdx.x == 0) *lossAcc = 0.0;
    const int wave = threadIdx.x >> 6;
    const int lane = threadIdx.x & 63;
    const int n = blockIdx.x * 4 + wave;
    const float4* xp = (const float4*)(x + (size_t)n * D_);
    float4* rp = (float4*)(R + (size_t)n * D_);
    double asum = 0.0;
#pragma unroll
    for (int u = 0; u < 2; ++u) {
        const int idx = u * 64 + lane;
        float4 v = xp[idx];
        rp[idx] = v;
        asum += (double)v.x * v.x + (double)v.y * v.y
              + (double)v.z * v.z + (double)v.w * v.w;
    }
#pragma unroll
    for (int off = 32; off > 0; off >>= 1)
        asum += __shfl_down(asum, off, 64);
    if (lane == 0) {
        rowNorm[n] = (float)asum;
        keys[n] = 0xFFFFFFFFFFFFFFFFull;
    }
}

// -------- distance GEMM + argmin --------
// M[n][k] = ascending-d fp32 FMA chain (bit-matches BLAS sgemm per element).
// comparator c = fl(rowNorm - 2*M); key = (bits(c)<<32)|k; u64 min ==
// lexicographic (c,k) min == np.argmin first-index tie rule.
// Round-1 loop shape (single-buffered, 2-barrier, compact VGPR) +
// conflict-free 4+4 split micro-tile + shuffle epilogue (LDS = 8 KB).
__global__ __launch_bounds__(256)
void rq_dist_argmin(const float* __restrict__ R, const float* __restrict__ E,
                    const float* __restrict__ rowNorm,
                    unsigned long long* __restrict__ keys)
{
    __shared__ float As[BKD][BM];
    __shared__ float Bs[BKD][BN];

    const int t  = threadIdx.x;
    const int tx = t & 15;
    const int ty = t >> 4;
    const int rowBase = blockIdx.y * BM;   // y = row tile (82)
    const int colBase = blockIdx.x * BN;   // x = col tile (32): adjacent blocks share the A row-tile -> L2 reuse

    const int lm   = t >> 1;         // 0..127: tile row loaded by this thread
    const int lseg = (t & 1) * 4;    // 0 or 4: d-offset within 8-wide slab

    const float* Aptr = R + (size_t)(rowBase + lm) * D_ + lseg;
    const float* Bptr = E + (size_t)(colBase + lm) * D_ + lseg;

    float acc[8][8];
#pragma unroll
    for (int i = 0; i < 8; ++i)
#pragma unroll
        for (int j = 0; j < 8; ++j) acc[i][j] = 0.0f;

    for (int dt = 0; dt < D_; dt += BKD) {
        const float4 av = *(const float4*)(Aptr + dt);
        const float4 bv = *(const float4*)(Bptr + dt);
        __syncthreads();
        As[lseg + 0][lm] = av.x; As[lseg + 1][lm] = av.y;
        As[lseg + 2][lm] = av.z; As[lseg + 3][lm] = av.w;
        Bs[lseg + 0][lm] = bv.x; Bs[lseg + 1][lm] = bv.y;
        Bs[lseg + 2][lm] = bv.z; Bs[lseg + 3][lm] = bv.w;
        __syncthreads();
#pragma unroll
        for (int dd = 0; dd < BKD; ++dd) {   // ascending d: exact chain order
            float a[8], b[8];
            *(float4*)&a[0] = *(const float4*)&As[dd][ty * 4];
            *(float4*)&a[4] = *(const float4*)&As[dd][ty * 4 + 64];
            *(float4*)&b[0] = *(const float4*)&Bs[dd][tx * 4];
            *(float4*)&b[4] = *(const float4*)&Bs[dd][tx * 4 + 64];
#pragma unroll
            for (int i = 0; i < 8; ++i)
#pragma unroll
                for (int j = 0; j < 8; ++j)
                    acc[i][j] = fmaf(a[i], b[j], acc[i][j]);
        }
    }

    // epilogue: per-thread keys, shuffle-reduce across tx (lane bits 0..3),
    // then one atomicMin per (row, tx==0) lane.
#pragma unroll
    for (int i = 0; i < 8; ++i) {
        const int rl = ty * 4 + (i & 3) + ((i >= 4) ? 64 : 0);
        const float An = rowNorm[rowBase + rl];
        unsigned long long best = 0xFFFFFFFFFFFFFFFFull;
#pragma unroll
        for (int j = 0; j < 8; ++j) {
            const int col = colBase + tx * 4 + (j & 3) + ((j >= 4) ? 64 : 0);
            const float c = __fsub_rn(An, 2.0f * acc[i][j]);  // c > 0 always
            const unsigned long long key =
                ((unsigned long long)__float_as_uint(c) << 32)
                | (unsigned int)col;
            if (key < best) best = key;
        }
#pragma unroll
        for (int m = 1; m < 16; m <<= 1) {
            const unsigned long long o = __shfl_xor(best, m, 64);
            if (o < best) best = o;
        }
        if (tx == 0)
            atomicMin(&keys[rowBase + rl], best);
    }
}

// -------- per-layer update: STE epilogue, exact fp32 replication --------
__global__ __launch_bounds__(256)
void rq_update(float* __restrict__ R, const float* __restrict__ E,
               unsigned long long* __restrict__ keys,
               float* __restrict__ qout, float* __restrict__ idxOut,
               float* __restrict__ rowNorm, double* __restrict__ lossAcc,
               int layer)
{
    const int wave = threadIdx.x >> 6;
    const int lane = threadIdx.x & 63;
    const int n = blockIdx.x * 4 + wave;
    const unsigned long long key = keys[n];
    const int k = (int)(key & 0xFFFFFFFFull);

    const float4* ep = (const float4*)(E + (size_t)k * D_);
    float4* rp = (float4*)(R + (size_t)n * D_);
    float4* qp = (float4*)(qout + (size_t)n * D_);

    double lsum = 0.0, asum = 0.0;
#pragma unroll
    for (int u = 0; u < 2; ++u) {
        const int idx = u * 64 + lane;
        float4 r4 = rp[idx];
        float4 q4 = ep[idx];
        float4 o4 = (layer == 0) ? make_float4(0.f, 0.f, 0.f, 0.f) : qp[idx];
        float rnew[4], qo[4];
        float rr[4] = {r4.x, r4.y, r4.z, r4.w};
        float qq[4] = {q4.x, q4.y, q4.z, q4.w};
        float oo[4] = {o4.x, o4.y, o4.z, o4.w};
#pragma unroll
        for (int c = 0; c < 4; ++c) {
            const float d1  = __fsub_rn(qq[c], rr[c]);   // quantized - residual
            const float qst = __fadd_rn(rr[c], d1);      // straight-through value
            rnew[c] = __fsub_rn(rr[c], qst);
            qo[c]   = __fadd_rn(oo[c], qst);
            lsum += (double)d1 * (double)d1;
            asum += (double)rnew[c] * (double)rnew[c];
        }
        rp[idx] = make_float4(rnew[0], rnew[1], rnew[2], rnew[3]);
        qp[idx] = make_float4(qo[0], qo[1], qo[2], qo[3]);
    }
#pragma unroll
    for (int off = 32; off > 0; off >>= 1) {
        lsum += __shfl_down(lsum, off, 64);
        asum += __shfl_down(asum, off, 64);
    }
    if (lane == 0) {
        rowNorm[n] = (float)asum;
        keys[n] = 0xFFFFFFFFFFFFFFFFull;   // re-arm for next layer
        atomicAdd(lossAcc, lsum);
        idxOut[(size_t)n * L_ + layer] = (float)k;
    }
}

__global__ void rq_finalize(float* __restrict__ lossOut,
                            const double* __restrict__ lossAcc)
{
    *lossOut = (float)(0.25 * (*lossAcc) / (double)QOUT_ELEMS);
}

extern "C" void kernel_launch(void* const* d_in, const int* in_sizes, int n_in,
                              void* d_out, int out_size, void* d_ws, size_t ws_size,
                              hipStream_t stream)
{
    const float* x  = (const float*)d_in[0];
    const float* cb = (const float*)d_in[1];
    float* out = (float*)d_out;
    char* ws = (char*)d_ws;

    float* R = (float*)ws;                                     // 21,495,808 B
    float* rowNorm = (float*)(ws + 21495808);                  //     41,984 B
    unsigned long long* keys = (unsigned long long*)(ws + 21537792); // 83,968 B
    double* lossAcc = (double*)(ws + 21621760);                //          8 B

    float* idxOut = out + QOUT_ELEMS + 1;

    rq_init<<<NROWS / 4, 256, 0, stream>>>(x, R, rowNorm, keys, lossAcc);

    for (int l = 0; l < L_; ++l) {
        const float* E = cb + (size_t)l * K_ * D_;
        dim3 grid(K_ / BN, NROWS / BM);   // x = col tile, y = row tile
        rq_dist_argmin<<<grid, 256, 0, stream>>>(R, E, rowNorm, keys);
        rq_update<<<NROWS / 4, 256, 0, stream>>>(R, E, keys, out, idxOut,
                                                 rowNorm, lossAcc, l);
    }
    rq_finalize<<<1, 1, 0, stream>>>(out + QOUT_ELEMS, lossAcc);
}

// Round 4
// 5328.384 us; speedup vs baseline: 1.3901x; 1.0020x over previous
//
#include <hip/hip_runtime.h>
#include <cstdint>
#include <cstddef>

#define B_    256
#define W_    41
#define D_    512
#define K_    4096
#define L_    8
#define NROWS (B_ * W_)            // 10496
#define QOUT_ELEMS (NROWS * D_)    // 5373952

#define BM 128
#define BN 128
#define BKD 8
#define NT (D_ / BKD)              // 64 k-tiles

// -------- init: residual = x, rowNorm[n] = (float)sum(x^2), arm keys --------
__global__ __launch_bounds__(256)
void rq_init(const float* __restrict__ x, float* __restrict__ R,
             float* __restrict__ rowNorm, unsigned long long* __restrict__ keys,
             double* __restrict__ lossAcc)
{
    if (blockIdx.x == 0 && threadIdx.x == 0) *lossAcc = 0.0;
    const int wave = threadIdx.x >> 6;
    const int lane = threadIdx.x & 63;
    const int n = blockIdx.x * 4 + wave;
    const float4* xp = (const float4*)(x + (size_t)n * D_);
    float4* rp = (float4*)(R + (size_t)n * D_);
    double asum = 0.0;
#pragma unroll
    for (int u = 0; u < 2; ++u) {
        const int idx = u * 64 + lane;
        float4 v = xp[idx];
        rp[idx] = v;
        asum += (double)v.x * v.x + (double)v.y * v.y
              + (double)v.z * v.z + (double)v.w * v.w;
    }
#pragma unroll
    for (int off = 32; off > 0; off >>= 1)
        asum += __shfl_down(asum, off, 64);
    if (lane == 0) {
        rowNorm[n] = (float)asum;
        keys[n] = 0xFFFFFFFFFFFFFFFFull;
    }
}

// -------- distance GEMM + argmin --------
// M[n][k] = ascending-d fp32 FMA chain (bit-matches BLAS sgemm per element).
// comparator c = fl(rowNorm - 2*M); key = (bits(c)<<32)|k; u64 min ==
// lexicographic (c,k) min == np.argmin first-index tie rule.
// Single LDS buffer + REGISTER prefetch of tile t+1 issued before computing
// tile t: the 1024-FMA compute + barrier hides the global-load latency that
// round 3 exposed on every k-iteration. 8 stage VGPRs only (BKD=8);
// unroll 1 on the k-loop keeps the allocator compact (round-2 lesson).
__global__ __launch_bounds__(256)
void rq_dist_argmin(const float* __restrict__ R, const float* __restrict__ E,
                    const float* __restrict__ rowNorm,
                    unsigned long long* __restrict__ keys)
{
    __shared__ float As[BKD][BM];
    __shared__ float Bs[BKD][BN];

    const int t  = threadIdx.x;
    const int tx = t & 15;
    const int ty = t >> 4;
    const int rowBase = blockIdx.y * BM;   // y = row tile (82)
    const int colBase = blockIdx.x * BN;   // x = col tile (32): adjacent blocks share the A row-tile -> L2 reuse

    const int lm   = t >> 1;         // 0..127: tile row loaded by this thread
    const int lseg = (t & 1) * 4;    // 0 or 4: d-offset within 8-wide slab

    const float* Aptr = R + (size_t)(rowBase + lm) * D_ + lseg;
    const float* Bptr = E + (size_t)(colBase + lm) * D_ + lseg;

    float acc[8][8];
#pragma unroll
    for (int i = 0; i < 8; ++i)
#pragma unroll
        for (int j = 0; j < 8; ++j) acc[i][j] = 0.0f;

    // stage tile 0 into LDS
    {
        const float4 av = *(const float4*)(Aptr);
        const float4 bv = *(const float4*)(Bptr);
        As[lseg + 0][lm] = av.x; As[lseg + 1][lm] = av.y;
        As[lseg + 2][lm] = av.z; As[lseg + 3][lm] = av.w;
        Bs[lseg + 0][lm] = bv.x; Bs[lseg + 1][lm] = bv.y;
        Bs[lseg + 2][lm] = bv.z; Bs[lseg + 3][lm] = bv.w;
    }
    __syncthreads();

#pragma unroll 1
    for (int tile = 0; tile < NT; ++tile) {
        // issue next tile's loads BEFORE compute — latency hidden by the
        // 512 FMA instructions + barrier below.
        float4 av, bv;
        const bool more = (tile + 1) < NT;
        if (more) {
            const int dt = (tile + 1) * BKD;
            av = *(const float4*)(Aptr + dt);
            bv = *(const float4*)(Bptr + dt);
        }
#pragma unroll
        for (int dd = 0; dd < BKD; ++dd) {   // ascending d: exact chain order
            float a[8], b[8];
            *(float4*)&a[0] = *(const float4*)&As[dd][ty * 4];
            *(float4*)&a[4] = *(const float4*)&As[dd][ty * 4 + 64];
            *(float4*)&b[0] = *(const float4*)&Bs[dd][tx * 4];
            *(float4*)&b[4] = *(const float4*)&Bs[dd][tx * 4 + 64];
#pragma unroll
            for (int i = 0; i < 8; ++i)
#pragma unroll
                for (int j = 0; j < 8; ++j)
                    acc[i][j] = fmaf(a[i], b[j], acc[i][j]);
        }
        __syncthreads();              // all waves done reading tile `tile`
        if (more) {
            As[lseg + 0][lm] = av.x; As[lseg + 1][lm] = av.y;
            As[lseg + 2][lm] = av.z; As[lseg + 3][lm] = av.w;
            Bs[lseg + 0][lm] = bv.x; Bs[lseg + 1][lm] = bv.y;
            Bs[lseg + 2][lm] = bv.z; Bs[lseg + 3][lm] = bv.w;
        }
        __syncthreads();              // tile+1 visible
    }

    // epilogue: per-thread keys, shuffle-reduce across tx (lane bits 0..3),
    // then one atomicMin per (row, tx==0) lane.
#pragma unroll
    for (int i = 0; i < 8; ++i) {
        const int rl = ty * 4 + (i & 3) + ((i >= 4) ? 64 : 0);
        const float An = rowNorm[rowBase + rl];
        unsigned long long best = 0xFFFFFFFFFFFFFFFFull;
#pragma unroll
        for (int j = 0; j < 8; ++j) {
            const int col = colBase + tx * 4 + (j & 3) + ((j >= 4) ? 64 : 0);
            const float c = __fsub_rn(An, 2.0f * acc[i][j]);  // c > 0 always
            const unsigned long long key =
                ((unsigned long long)__float_as_uint(c) << 32)
                | (unsigned int)col;
            if (key < best) best = key;
        }
#pragma unroll
        for (int m = 1; m < 16; m <<= 1) {
            const unsigned long long o = __shfl_xor(best, m, 64);
            if (o < best) best = o;
        }
        if (tx == 0)
            atomicMin(&keys[rowBase + rl], best);
    }
}

// -------- per-layer update: STE epilogue, exact fp32 replication --------
__global__ __launch_bounds__(256)
void rq_update(float* __restrict__ R, const float* __restrict__ E,
               unsigned long long* __restrict__ keys,
               float* __restrict__ qout, float* __restrict__ idxOut,
               float* __restrict__ rowNorm, double* __restrict__ lossAcc,
               int layer)
{
    const int wave = threadIdx.x >> 6;
    const int lane = threadIdx.x & 63;
    const int n = blockIdx.x * 4 + wave;
    const unsigned long long key = keys[n];
    const int k = (int)(key & 0xFFFFFFFFull);

    const float4* ep = (const float4*)(E + (size_t)k * D_);
    float4* rp = (float4*)(R + (size_t)n * D_);
    float4* qp = (float4*)(qout + (size_t)n * D_);

    double lsum = 0.0, asum = 0.0;
#pragma unroll
    for (int u = 0; u < 2; ++u) {
        const int idx = u * 64 + lane;
        float4 r4 = rp[idx];
        float4 q4 = ep[idx];
        float4 o4 = (layer == 0) ? make_float4(0.f, 0.f, 0.f, 0.f) : qp[idx];
        float rnew[4], qo[4];
        float rr[4] = {r4.x, r4.y, r4.z, r4.w};
        float qq[4] = {q4.x, q4.y, q4.z, q4.w};
        float oo[4] = {o4.x, o4.y, o4.z, o4.w};
#pragma unroll
        for (int c = 0; c < 4; ++c) {
            const float d1  = __fsub_rn(qq[c], rr[c]);   // quantized - residual
            const float qst = __fadd_rn(rr[c], d1);      // straight-through value
            rnew[c] = __fsub_rn(rr[c], qst);
            qo[c]   = __fadd_rn(oo[c], qst);
            lsum += (double)d1 * (double)d1;
            asum += (double)rnew[c] * (double)rnew[c];
        }
        rp[idx] = make_float4(rnew[0], rnew[1], rnew[2], rnew[3]);
        qp[idx] = make_float4(qo[0], qo[1], qo[2], qo[3]);
    }
#pragma unroll
    for (int off = 32; off > 0; off >>= 1) {
        lsum += __shfl_down(lsum, off, 64);
        asum += __shfl_down(asum, off, 64);
    }
    if (lane == 0) {
        rowNorm[n] = (float)asum;
        keys[n] = 0xFFFFFFFFFFFFFFFFull;   // re-arm for next layer
        atomicAdd(lossAcc, lsum);
        idxOut[(size_t)n * L_ + layer] = (float)k;
    }
}

__global__ void rq_finalize(float* __restrict__ lossOut,
                            const double* __restrict__ lossAcc)
{
    *lossOut = (float)(0.25 * (*lossAcc) / (double)QOUT_ELEMS);
}

extern "C" void kernel_launch(void* const* d_in, const int* in_sizes, int n_in,
                              void* d_out, int out_size, void* d_ws, size_t ws_size,
                              hipStream_t stream)
{
    const float* x  = (const float*)d_in[0];
    const float* cb = (const float*)d_in[1];
    float* out = (float*)d_out;
    char* ws = (char*)d_ws;

    float* R = (float*)ws;                                     // 21,495,808 B
    float* rowNorm = (float*)(ws + 21495808);                  //     41,984 B
    unsigned long long* keys = (unsigned long long*)(ws + 21537792); // 83,968 B
    double* lossAcc = (double*)(ws + 21621760);                //          8 B

    float* idxOut = out + QOUT_ELEMS + 1;

    rq_init<<<NROWS / 4, 256, 0, stream>>>(x, R, rowNorm, keys, lossAcc);

    for (int l = 0; l < L_; ++l) {
        const float* E = cb + (size_t)l * K_ * D_;
        dim3 grid(K_ / BN, NROWS / BM);   // x = col tile, y = row tile
        rq_dist_argmin<<<grid, 256, 0, stream>>>(R, E, rowNorm, keys);
        rq_update<<<NROWS / 4, 256, 0, stream>>>(R, E, keys, out, idxOut,
                                                 rowNorm, lossAcc, l);
    }
    rq_finalize<<<1, 1, 0, stream>>>(out + QOUT_ELEMS, lossAcc);
}

// Round 5
// 4373.792 us; speedup vs baseline: 1.6935x; 1.2183x over previous
//
#include <hip/hip_runtime.h>
#include <cstdint>
#include <cstddef>

#define B_    256
#define W_    41
#define D_    512
#define K_    4096
#define L_    8
#define NROWS (B_ * W_)            // 10496
#define QOUT_ELEMS (NROWS * D_)    // 5373952

#define BM 128
#define BN 128
#define BKD 8

// -------- init: residual = x, rowNorm[n] = (float)sum(x^2), arm keys --------
__global__ __launch_bounds__(256)
void rq_init(const float* __restrict__ x, float* __restrict__ R,
             float* __restrict__ rowNorm, unsigned long long* __restrict__ keys)
{
    const int wave = threadIdx.x >> 6;
    const int lane = threadIdx.x & 63;
    const int n = blockIdx.x * 4 + wave;
    const float4* xp = (const float4*)(x + (size_t)n * D_);
    float4* rp = (float4*)(R + (size_t)n * D_);
    double asum = 0.0;
#pragma unroll
    for (int u = 0; u < 2; ++u) {
        const int idx = u * 64 + lane;
        float4 v = xp[idx];
        rp[idx] = v;
        asum += (double)v.x * v.x + (double)v.y * v.y
              + (double)v.z * v.z + (double)v.w * v.w;
    }
#pragma unroll
    for (int off = 32; off > 0; off >>= 1)
        asum += __shfl_down(asum, off, 64);
    if (lane == 0) {
        rowNorm[n] = (float)asum;
        keys[n] = 0xFFFFFFFFFFFFFFFFull;
    }
}

// -------- distance GEMM + argmin (round-3 verbatim: the proven best) ------
// M[n][k] = ascending-d fp32 FMA chain (bit-matches BLAS sgemm per element).
// comparator c = fl(rowNorm - 2*M); key = (bits(c)<<32)|k; u64 min ==
// lexicographic (c,k) min == np.argmin first-index tie rule.
// Single-buffered 2-barrier K-loop, 52 VGPR, ~3 blocks/CU: measured optimum
// (register prefetch / LDS dbuf variants regress via VGPR pressure).
__global__ __launch_bounds__(256)
void rq_dist_argmin(const float* __restrict__ R, const float* __restrict__ E,
                    const float* __restrict__ rowNorm,
                    unsigned long long* __restrict__ keys)
{
    __shared__ float As[BKD][BM];
    __shared__ float Bs[BKD][BN];

    const int t  = threadIdx.x;
    const int tx = t & 15;
    const int ty = t >> 4;
    const int rowBase = blockIdx.y * BM;   // y = row tile (82)
    const int colBase = blockIdx.x * BN;   // x = col tile (32): adjacent blocks share the A row-tile -> L2 reuse

    const int lm   = t >> 1;         // 0..127: tile row loaded by this thread
    const int lseg = (t & 1) * 4;    // 0 or 4: d-offset within 8-wide slab

    const float* Aptr = R + (size_t)(rowBase + lm) * D_ + lseg;
    const float* Bptr = E + (size_t)(colBase + lm) * D_ + lseg;

    float acc[8][8];
#pragma unroll
    for (int i = 0; i < 8; ++i)
#pragma unroll
        for (int j = 0; j < 8; ++j) acc[i][j] = 0.0f;

    for (int dt = 0; dt < D_; dt += BKD) {
        const float4 av = *(const float4*)(Aptr + dt);
        const float4 bv = *(const float4*)(Bptr + dt);
        __syncthreads();
        As[lseg + 0][lm] = av.x; As[lseg + 1][lm] = av.y;
        As[lseg + 2][lm] = av.z; As[lseg + 3][lm] = av.w;
        Bs[lseg + 0][lm] = bv.x; Bs[lseg + 1][lm] = bv.y;
        Bs[lseg + 2][lm] = bv.z; Bs[lseg + 3][lm] = bv.w;
        __syncthreads();
#pragma unroll
        for (int dd = 0; dd < BKD; ++dd) {   // ascending d: exact chain order
            float a[8], b[8];
            *(float4*)&a[0] = *(const float4*)&As[dd][ty * 4];
            *(float4*)&a[4] = *(const float4*)&As[dd][ty * 4 + 64];
            *(float4*)&b[0] = *(const float4*)&Bs[dd][tx * 4];
            *(float4*)&b[4] = *(const float4*)&Bs[dd][tx * 4 + 64];
#pragma unroll
            for (int i = 0; i < 8; ++i)
#pragma unroll
                for (int j = 0; j < 8; ++j)
                    acc[i][j] = fmaf(a[i], b[j], acc[i][j]);
        }
    }

    // epilogue: per-thread keys, shuffle-reduce across tx (lane bits 0..3),
    // then one atomicMin per (row, tx==0) lane.
#pragma unroll
    for (int i = 0; i < 8; ++i) {
        const int rl = ty * 4 + (i & 3) + ((i >= 4) ? 64 : 0);
        const float An = rowNorm[rowBase + rl];
        unsigned long long best = 0xFFFFFFFFFFFFFFFFull;
#pragma unroll
        for (int j = 0; j < 8; ++j) {
            const int col = colBase + tx * 4 + (j & 3) + ((j >= 4) ? 64 : 0);
            const float c = __fsub_rn(An, 2.0f * acc[i][j]);  // c > 0 always
            const unsigned long long key =
                ((unsigned long long)__float_as_uint(c) << 32)
                | (unsigned int)col;
            if (key < best) best = key;
        }
#pragma unroll
        for (int m = 1; m < 16; m <<= 1) {
            const unsigned long long o = __shfl_xor(best, m, 64);
            if (o < best) best = o;
        }
        if (tx == 0)
            atomicMin(&keys[rowBase + rl], best);
    }
}

// -------- per-layer update: STE epilogue, exact fp32 replication ----------
// Loss: NO single-address atomic (round-3 profile: 10496 serialized f64
// atomics ~= 300 us/layer). Each wave exclusively owns row n -> plain
// read-modify-write of lossPartial[n] across layers.
__global__ __launch_bounds__(256)
void rq_update(float* __restrict__ R, const float* __restrict__ E,
               unsigned long long* __restrict__ keys,
               float* __restrict__ qout, float* __restrict__ idxOut,
               float* __restrict__ rowNorm, double* __restrict__ lossPartial,
               int layer)
{
    const int wave = threadIdx.x >> 6;
    const int lane = threadIdx.x & 63;
    const int n = blockIdx.x * 4 + wave;
    const unsigned long long key = keys[n];
    const int k = (int)(key & 0xFFFFFFFFull);

    const float4* ep = (const float4*)(E + (size_t)k * D_);
    float4* rp = (float4*)(R + (size_t)n * D_);
    float4* qp = (float4*)(qout + (size_t)n * D_);

    double lsum = 0.0, asum = 0.0;
#pragma unroll
    for (int u = 0; u < 2; ++u) {
        const int idx = u * 64 + lane;
        float4 r4 = rp[idx];
        float4 q4 = ep[idx];
        float4 o4 = (layer == 0) ? make_float4(0.f, 0.f, 0.f, 0.f) : qp[idx];
        float rnew[4], qo[4];
        float rr[4] = {r4.x, r4.y, r4.z, r4.w};
        float qq[4] = {q4.x, q4.y, q4.z, q4.w};
        float oo[4] = {o4.x, o4.y, o4.z, o4.w};
#pragma unroll
        for (int c = 0; c < 4; ++c) {
            const float d1  = __fsub_rn(qq[c], rr[c]);   // quantized - residual
            const float qst = __fadd_rn(rr[c], d1);      // straight-through value
            rnew[c] = __fsub_rn(rr[c], qst);
            qo[c]   = __fadd_rn(oo[c], qst);
            lsum += (double)d1 * (double)d1;
            asum += (double)rnew[c] * (double)rnew[c];
        }
        rp[idx] = make_float4(rnew[0], rnew[1], rnew[2], rnew[3]);
        qp[idx] = make_float4(qo[0], qo[1], qo[2], qo[3]);
    }
#pragma unroll
    for (int off = 32; off > 0; off >>= 1) {
        lsum += __shfl_down(lsum, off, 64);
        asum += __shfl_down(asum, off, 64);
    }
    if (lane == 0) {
        rowNorm[n] = (float)asum;
        keys[n] = 0xFFFFFFFFFFFFFFFFull;   // re-arm for next layer
        lossPartial[n] = (layer == 0) ? lsum : (lossPartial[n] + lsum);
        idxOut[(size_t)n * L_ + layer] = (float)k;
    }
}

// -------- finalize: sum 10496 per-row partials, scale ----------
__global__ __launch_bounds__(256)
void rq_finalize(float* __restrict__ lossOut,
                 const double* __restrict__ lossPartial)
{
    __shared__ double ws[4];
    const int t = threadIdx.x;
    double s = 0.0;
    for (int i = t; i < NROWS; i += 256) s += lossPartial[i];
#pragma unroll
    for (int off = 32; off > 0; off >>= 1)
        s += __shfl_down(s, off, 64);
    if ((t & 63) == 0) ws[t >> 6] = s;
    __syncthreads();
    if (t == 0) {
        double tot = ws[0] + ws[1] + ws[2] + ws[3];
        *lossOut = (float)(0.25 * tot / (double)QOUT_ELEMS);
    }
}

extern "C" void kernel_launch(void* const* d_in, const int* in_sizes, int n_in,
                              void* d_out, int out_size, void* d_ws, size_t ws_size,
                              hipStream_t stream)
{
    const float* x  = (const float*)d_in[0];
    const float* cb = (const float*)d_in[1];
    float* out = (float*)d_out;
    char* ws = (char*)d_ws;

    float* R = (float*)ws;                                     // 21,495,808 B
    float* rowNorm = (float*)(ws + 21495808);                  //     41,984 B
    unsigned long long* keys = (unsigned long long*)(ws + 21537792); // 83,968 B
    double* lossPartial = (double*)(ws + 21621760);            //     83,968 B

    float* idxOut = out + QOUT_ELEMS + 1;

    rq_init<<<NROWS / 4, 256, 0, stream>>>(x, R, rowNorm, keys);

    for (int l = 0; l < L_; ++l) {
        const float* E = cb + (size_t)l * K_ * D_;
        dim3 grid(K_ / BN, NROWS / BM);   // x = col tile, y = row tile
        rq_dist_argmin<<<grid, 256, 0, stream>>>(R, E, rowNorm, keys);
        rq_update<<<NROWS / 4, 256, 0, stream>>>(R, E, keys, out, idxOut,
                                                 rowNorm, lossPartial, l);
    }
    rq_finalize<<<1, 256, 0, stream>>>(out + QOUT_ELEMS, lossPartial);
}